// Round 4
// baseline (182.447 us; speedup 1.0000x reference)
//
#include <hip/hip_runtime.h>
#include <hip/hip_bf16.h>

// Problem constants
#define D       512       // embedding dim (= C)
#define K       2048      // codebook size
#define HW      1024      // 32*32
#define N_TOK   16384     // 16*HW
#define NUMEL   8388608   // 16*512*32*32

typedef __attribute__((ext_vector_type(8))) short  short8;   // 8 bf16 = 4 VGPRs
typedef __attribute__((ext_vector_type(4))) float  floatx4;

// async global->LDS DMA, 16 B per lane; LDS dest is wave-uniform base + lane*16
#define GLD_LDS16(gptr, lptr) \
    __builtin_amdgcn_global_load_lds((const __attribute__((address_space(1))) void*)(gptr), \
                                     (__attribute__((address_space(3))) void*)(lptr), 16, 0, 0)

// ---- ws layout (bytes) ----
#define WS_ZB    0           // bf16 [16384][512]
#define WS_EB    16777216    // bf16 [2048][512]
#define WS_ESQ   18874368    // f32  [2048]
#define WS_MINB  18882560    // u32  [16384] packed (21-bit dist key | 11-bit idx); init in kp
#define WS_PZ    18948096    // f32  [2048]  per-kp-block sum z^2 partials (plain writes)
#define WS_PARTS 18956288    // f32  [256]   per-strip decoded-key partials (plain writes)
#define WS_CNT2  18957312    // u32  [1]     completion counter (zeroed by kp)

// monotone fp32 -> sortable u32, and its inverse
__device__ __forceinline__ unsigned int fkey(float f) {
    unsigned int b = __float_as_uint(f);
    return b ^ ((unsigned int)((int)b >> 31) | 0x80000000u);
}
__device__ __forceinline__ float unfkey(unsigned int u) {
    unsigned int b = (u & 0x80000000u) ? (u ^ 0x80000000u) : ~u;
    return __uint_as_float(b);
}

// ---------------- Kernel P: fused prep (unchanged — control) ----------------
__global__ __launch_bounds__(256) void kp(const float* __restrict__ z,
                                          const float* __restrict__ emb,
                                          __hip_bfloat16* __restrict__ zb,
                                          __hip_bfloat16* __restrict__ eb,
                                          float* __restrict__ esq,
                                          float* __restrict__ pz,
                                          unsigned int* __restrict__ minb,
                                          unsigned int* __restrict__ cnt2) {
    int blk = blockIdx.x;
    int tid = threadIdx.x;
    if (blk < 2048) {
        if (tid < 8) minb[blk * 8 + tid] = 0xFFFFFFFFu;
        if (blk == 0 && tid == 8) *cnt2 = 0u;
        __shared__ float t[64][65];
        __shared__ float ls[4];
        int b  = blk >> 7;
        int dt = (blk >> 4) & 7;
        int nt = blk & 15;
        int d0 = dt * 64, n0 = nt * 64;
        const float* zp = z + ((size_t)b * D + d0) * HW + n0;
        float s = 0.f;
#pragma unroll
        for (int i = 0; i < 4; ++i) {
            int e = tid + 256 * i;
            int r = e >> 4, c4 = e & 15;
            float4 v = *(const float4*)(zp + (size_t)r * HW + c4 * 4);
            s += v.x * v.x + v.y * v.y + v.z * v.z + v.w * v.w;
            t[r][c4 * 4 + 0] = v.x; t[r][c4 * 4 + 1] = v.y;
            t[r][c4 * 4 + 2] = v.z; t[r][c4 * 4 + 3] = v.w;
        }
#pragma unroll
        for (int o = 32; o; o >>= 1) s += __shfl_down(s, o);
        if ((tid & 63) == 0) ls[tid >> 6] = s;
        __syncthreads();
        if (tid == 0) pz[blk] = ls[0] + ls[1] + ls[2] + ls[3];
        __hip_bfloat16* op = zb + ((size_t)(b * HW + n0)) * D + d0;
#pragma unroll
        for (int i = 0; i < 4; ++i) {
            int e = tid + 256 * i;
            int rn = e >> 4, cd4 = e & 15;
            __hip_bfloat16 q0 = __float2bfloat16(t[cd4 * 4 + 0][rn]);
            __hip_bfloat16 q1 = __float2bfloat16(t[cd4 * 4 + 1][rn]);
            __hip_bfloat16 q2 = __float2bfloat16(t[cd4 * 4 + 2][rn]);
            __hip_bfloat16 q3 = __float2bfloat16(t[cd4 * 4 + 3][rn]);
            ushort4 u;
            u.x = *(unsigned short*)&q0; u.y = *(unsigned short*)&q1;
            u.z = *(unsigned short*)&q2; u.w = *(unsigned short*)&q3;
            *(ushort4*)(op + (size_t)rn * D + cd4 * 4) = u;
        }
    } else {
        int k = blk - 2048;
        const float* ep = emb + (size_t)k * D;
        float s = 0.f;
        for (int d = tid; d < D; d += 256) {
            float v = ep[d];
            s += v * v;
            eb[(size_t)k * D + d] = __float2bfloat16(v);
        }
#pragma unroll
        for (int o = 32; o; o >>= 1) s += __shfl_down(s, o);
        __shared__ float ls[4];
        if ((tid & 63) == 0) ls[tid >> 6] = s;
        __syncthreads();
        if (tid == 0) esq[k] = ls[0] + ls[1] + ls[2] + ls[3];
    }
}

// ---------------- Kernel G4: 256x256 tile, 8-wave, BK=64 dbuf (unchanged — control) ----------------
__global__ __launch_bounds__(512, 2) void kg(const __hip_bfloat16* __restrict__ zb,
                                             const __hip_bfloat16* __restrict__ eb,
                                             const float* __restrict__ esq,
                                             unsigned int* __restrict__ minb) {
    __shared__ __hip_bfloat16 As[2][256 * 64];   // 32 KiB per slot
    __shared__ __hip_bfloat16 Bs[2][256 * 64];   // total 128 KiB

    int bid   = blockIdx.x;
    int swzb  = (bid & 7) * 64 + (bid >> 3);
    int mtile = swzb >> 3;            // 0..63
    int ntile = swzb & 7;             // 0..7

    int tid  = threadIdx.x;
    int wv   = tid >> 6;              // 0..7
    int lane = tid & 63;
    int wm   = wv >> 2, wnn = wv & 3; // 2x4 wave grid, wave tile 128(M) x 64(N)
    int lrow = lane & 15, lquad = lane >> 4;
    int rl8  = lane >> 3, c8 = lane & 7;     // staging: 8 rows x 8 uint4 per wave-call
    int csw  = c8 ^ (rl8 & 7);               // store-side swizzled global uint4 col
    int swz  = lrow & 7;                     // read-side swizzle key

    const uint4* Ag = (const uint4*)(zb + (size_t)mtile * 256 * D);  // row stride 64 uint4
    const uint4* Bg = (const uint4*)(eb + (size_t)ntile * 256 * D);

    floatx4 acc[8][4];
#pragma unroll
    for (int f = 0; f < 8; ++f)
#pragma unroll
        for (int g = 0; g < 4; ++g) acc[f][g] = (floatx4){0.f, 0.f, 0.f, 0.f};

#define STAGE(sl, t) do {                                                                  \
        _Pragma("unroll")                                                                  \
        for (int q = 0; q < 4; ++q) {                                                      \
            int rb = wv * 32 + q * 8;      /* wave-uniform row base */                     \
            GLD_LDS16(Ag + (size_t)(rb + rl8) * 64 + (t) * 8 + csw, &As[sl][rb * 64]);     \
            GLD_LDS16(Bg + (size_t)(rb + rl8) * 64 + (t) * 8 + csw, &Bs[sl][rb * 64]);     \
        }                                                                                  \
    } while (0)

#define STEP(sl) do {                                                                      \
        _Pragma("unroll")                                                                  \
        for (int kh = 0; kh < 2; ++kh) {                                                   \
            short8 bf[4], af[8];                                                           \
            const int cL = ((kh * 4 + lquad) ^ swz) << 3;                                  \
            _Pragma("unroll")                                                              \
            for (int g = 0; g < 4; ++g)                                                    \
                bf[g] = *(const short8*)&Bs[sl][(wnn * 64 + g * 16 + lrow) * 64 + cL];     \
            _Pragma("unroll")                                                              \
            for (int f = 0; f < 8; ++f)                                                    \
                af[f] = *(const short8*)&As[sl][(wm * 128 + f * 16 + lrow) * 64 + cL];     \
            _Pragma("unroll")                                                              \
            for (int f = 0; f < 8; ++f)                                                    \
                _Pragma("unroll")                                                          \
                for (int g = 0; g < 4; ++g)                                                \
                    acc[f][g] = __builtin_amdgcn_mfma_f32_16x16x32_bf16(af[f], bf[g],      \
                                                                        acc[f][g], 0, 0, 0);\
        }                                                                                  \
    } while (0)

    STAGE(0, 0);
    __syncthreads();

#pragma unroll
    for (int t = 0; t < 8; ++t) {
        if (t < 7) STAGE((t + 1) & 1, t + 1);
        STEP(t & 1);
        __syncthreads();
    }
#undef STAGE
#undef STEP

    float es[4];
#pragma unroll
    for (int g = 0; g < 4; ++g) es[g] = esq[ntile * 256 + wnn * 64 + g * 16 + lrow];

    unsigned int* scr = (unsigned int*)&As[0][0];
#pragma unroll
    for (int f = 0; f < 8; ++f) {
#pragma unroll
        for (int r = 0; r < 4; ++r) {
            unsigned int best = 0xFFFFFFFFu;
#pragma unroll
            for (int g = 0; g < 4; ++g) {
                float dist = es[g] - 2.0f * acc[f][g][r];
                unsigned int kidx = (unsigned int)(ntile * 256 + wnn * 64 + g * 16 + lrow);
                unsigned int p = (fkey(dist) & 0xFFFFF800u) | kidx;
                best = p < best ? p : best;
            }
#pragma unroll
            for (int o = 1; o < 16; o <<= 1) {
                unsigned int other = (unsigned int)__shfl_xor((int)best, o);
                best = other < best ? other : best;
            }
            if (lrow == 0)
                scr[wnn * 256 + wm * 128 + f * 16 + lquad * 4 + r] = best;
        }
    }
    __syncthreads();
    if (tid < 256) {
        unsigned int b0 = scr[tid];
        unsigned int b1 = scr[256 + tid];
        unsigned int b2 = scr[512 + tid];
        unsigned int b3 = scr[768 + tid];
        b0 = b1 < b0 ? b1 : b0;
        b2 = b3 < b2 ? b3 : b2;
        b0 = b2 < b0 ? b2 : b0;
        atomicMin(&minb[mtile * 256 + tid], b0);
    }
}

// ---------------- Kernel O4: gather + NCHW write + loss, FINE-GRAINED ----------------
// 2048 blocks x 256 thr: block = ONE 64-token x 64-channel subtile (was 512 blocks x 4
// subtiles x 2 halves). 16.9 KB LDS -> 8 blocks/CU -> 32 waves/CU (was 8): TLP now hides
// the gather(L2)->LDS->transpose->HBM chain that made the old ko3 latency-bound at
// 2 waves/SIMD. Loss partial lives in the sub==0 block of each strip; same cnt2/finflag
// protocol (last finishing sub==0 block folds parts[] + pz[] and writes out[NUMEL]).
__global__ __launch_bounds__(256) void ko3(const float* __restrict__ emb,
                                           const unsigned int* __restrict__ minb,
                                           const float* __restrict__ pz,
                                           float* __restrict__ out,
                                           float* __restrict__ parts,
                                           unsigned int* __restrict__ cnt2) {
    __shared__ int idx[64];
    __shared__ float qt[64][65];
    __shared__ float red[4];
    __shared__ int finflag;
    int blk   = blockIdx.x;           // 0..2047
    int strip = blk >> 3;             // 0..255 : token strip (b, hw0..hw0+63)
    int sub   = blk & 7;              // 0..7   : 64-channel subtile
    int b = strip >> 4, hw0 = (strip & 15) * 64;
    int c0 = sub * 64;
    int tid = threadIdx.x;
    unsigned int mykey = 0;
    if (tid < 64) {
        mykey = minb[strip * 64 + tid];
        idx[tid] = (int)(mykey & 0x7FFu);
    }
    if (tid == 0) finflag = 0;
    __syncthreads();

    // ---- loss partial (sub==0 blocks cover each token once) ----
    if (sub == 0 && tid < 64) {
        float v = unfkey(mykey & 0xFFFFF800u);   // min(esq - 2 dot) for this token
#pragma unroll
        for (int o = 32; o; o >>= 1) v += __shfl_down(v, o);
        if (tid == 0) {
            parts[strip] = v;
            __threadfence();
            finflag = (atomicAdd(cnt2, 1u) == 255u);
        }
    }

    // ---- gather subtile: 64 tokens x 64 channels, 256 B coalesced rows ----
#pragma unroll
    for (int i = 0; i < 4; ++i) {
        int e = tid + 256 * i;               // tr(64) x c4(16)
        int tr = e >> 4, c4 = e & 15;
        float4 v = *(const float4*)(emb + (size_t)idx[tr] * D + c0 + c4 * 4);
        qt[tr][c4 * 4 + 0] = v.x; qt[tr][c4 * 4 + 1] = v.y;
        qt[tr][c4 * 4 + 2] = v.z; qt[tr][c4 * 4 + 3] = v.w;
    }
    __syncthreads();

    // ---- transposed NCHW write: float4 along hw, 256 B per channel row ----
    float* op = out + ((size_t)b * D + c0) * HW + hw0;
#pragma unroll
    for (int i = 0; i < 4; ++i) {
        int e = tid + 256 * i;               // r(64 ch) x h4(16)
        int r = e >> 4, h4 = e & 15;
        float4 q;
        q.x = qt[h4 * 4 + 0][r]; q.y = qt[h4 * 4 + 1][r];
        q.z = qt[h4 * 4 + 2][r]; q.w = qt[h4 * 4 + 3][r];
        *(float4*)(op + (size_t)r * HW + h4 * 4) = q;
    }

    // ---- final loss reduce by the last-finishing sub==0 block ----
    __syncthreads();
    if (finflag) {
        float sv = atomicAdd(&parts[tid], 0.0f);    // coherent read of 256 strip partials
#pragma unroll
        for (int k8 = 0; k8 < 8; ++k8) sv += pz[tid * 8 + k8];   // fold 2048 z^2 partials
#pragma unroll
        for (int o = 32; o; o >>= 1) sv += __shfl_down(sv, o);
        if ((tid & 63) == 0) red[tid >> 6] = sv;
        __syncthreads();
        if (tid == 0)
            out[NUMEL] = 1.25f * (red[0] + red[1] + red[2] + red[3]) / 8388608.0f;
    }
}

extern "C" void kernel_launch(void* const* d_in, const int* in_sizes, int n_in,
                              void* d_out, int out_size, void* d_ws, size_t ws_size,
                              hipStream_t stream) {
    const float* z   = (const float*)d_in[0];   // [16,512,32,32]
    const float* emb = (const float*)d_in[1];   // [2048,512]
    char* ws = (char*)d_ws;
    __hip_bfloat16* zb   = (__hip_bfloat16*)(ws + WS_ZB);
    __hip_bfloat16* eb   = (__hip_bfloat16*)(ws + WS_EB);
    float*          esq  = (float*)(ws + WS_ESQ);
    unsigned int*   minb = (unsigned int*)(ws + WS_MINB);
    float*          pz   = (float*)(ws + WS_PZ);
    float*          parts= (float*)(ws + WS_PARTS);
    unsigned int*   cnt2 = (unsigned int*)(ws + WS_CNT2);
    float* out = (float*)d_out;

    kp <<<4096, 256, 0, stream>>>(z, emb, zb, eb, esq, pz, minb, cnt2);
    kg <<< 512, 512, 0, stream>>>(zb, eb, esq, minb);
    ko3<<<2048, 256, 0, stream>>>(emb, minb, pz, out, parts, cnt2);
}

// Round 5
// 147.487 us; speedup vs baseline: 1.2370x; 1.2370x over previous
//
#include <hip/hip_runtime.h>
#include <hip/hip_bf16.h>

// Problem constants
#define D       512       // embedding dim (= C)
#define K       2048      // codebook size
#define HW      1024      // 32*32
#define N_TOK   16384     // 16*HW
#define NUMEL   8388608   // 16*512*32*32

typedef __attribute__((ext_vector_type(8))) short  short8;   // 8 bf16 = 4 VGPRs
typedef __attribute__((ext_vector_type(4))) float  floatx4;

// async global->LDS DMA, 16 B per lane; LDS dest is wave-uniform base + lane*16
#define GLD_LDS16(gptr, lptr) \
    __builtin_amdgcn_global_load_lds((const __attribute__((address_space(1))) void*)(gptr), \
                                     (__attribute__((address_space(3))) void*)(lptr), 16, 0, 0)

// ---- ws layout (bytes) ----
#define WS_ZB    0           // bf16 [16384][512]
#define WS_EB    16777216    // bf16 [2048][512]
#define WS_ESQ   18874368    // f32  [2048]
#define WS_MINB  18882560    // u32  [16384] packed (21-bit dist key | 11-bit idx); init in kp
#define WS_PZ    18948096    // f32  [2048]  per-kp-block sum z^2 partials (plain writes)
#define WS_PARTS 18956288    // f32  [256]   per-image decoded-key partials (plain writes; 16 used)
#define WS_CNT2  18957312    // u32  [1]     completion counter (zeroed by kp)

// monotone fp32 -> sortable u32, and its inverse
__device__ __forceinline__ unsigned int fkey(float f) {
    unsigned int b = __float_as_uint(f);
    return b ^ ((unsigned int)((int)b >> 31) | 0x80000000u);
}
__device__ __forceinline__ float unfkey(unsigned int u) {
    unsigned int b = (u & 0x80000000u) ? (u ^ 0x80000000u) : ~u;
    return __uint_as_float(b);
}

// ---------------- Kernel P: fused prep (unchanged — control) ----------------
__global__ __launch_bounds__(256) void kp(const float* __restrict__ z,
                                          const float* __restrict__ emb,
                                          __hip_bfloat16* __restrict__ zb,
                                          __hip_bfloat16* __restrict__ eb,
                                          float* __restrict__ esq,
                                          float* __restrict__ pz,
                                          unsigned int* __restrict__ minb,
                                          unsigned int* __restrict__ cnt2) {
    int blk = blockIdx.x;
    int tid = threadIdx.x;
    if (blk < 2048) {
        if (tid < 8) minb[blk * 8 + tid] = 0xFFFFFFFFu;
        if (blk == 0 && tid == 8) *cnt2 = 0u;
        __shared__ float t[64][65];
        __shared__ float ls[4];
        int b  = blk >> 7;
        int dt = (blk >> 4) & 7;
        int nt = blk & 15;
        int d0 = dt * 64, n0 = nt * 64;
        const float* zp = z + ((size_t)b * D + d0) * HW + n0;
        float s = 0.f;
#pragma unroll
        for (int i = 0; i < 4; ++i) {
            int e = tid + 256 * i;
            int r = e >> 4, c4 = e & 15;
            float4 v = *(const float4*)(zp + (size_t)r * HW + c4 * 4);
            s += v.x * v.x + v.y * v.y + v.z * v.z + v.w * v.w;
            t[r][c4 * 4 + 0] = v.x; t[r][c4 * 4 + 1] = v.y;
            t[r][c4 * 4 + 2] = v.z; t[r][c4 * 4 + 3] = v.w;
        }
#pragma unroll
        for (int o = 32; o; o >>= 1) s += __shfl_down(s, o);
        if ((tid & 63) == 0) ls[tid >> 6] = s;
        __syncthreads();
        if (tid == 0) pz[blk] = ls[0] + ls[1] + ls[2] + ls[3];
        __hip_bfloat16* op = zb + ((size_t)(b * HW + n0)) * D + d0;
#pragma unroll
        for (int i = 0; i < 4; ++i) {
            int e = tid + 256 * i;
            int rn = e >> 4, cd4 = e & 15;
            __hip_bfloat16 q0 = __float2bfloat16(t[cd4 * 4 + 0][rn]);
            __hip_bfloat16 q1 = __float2bfloat16(t[cd4 * 4 + 1][rn]);
            __hip_bfloat16 q2 = __float2bfloat16(t[cd4 * 4 + 2][rn]);
            __hip_bfloat16 q3 = __float2bfloat16(t[cd4 * 4 + 3][rn]);
            ushort4 u;
            u.x = *(unsigned short*)&q0; u.y = *(unsigned short*)&q1;
            u.z = *(unsigned short*)&q2; u.w = *(unsigned short*)&q3;
            *(ushort4*)(op + (size_t)rn * D + cd4 * 4) = u;
        }
    } else {
        int k = blk - 2048;
        const float* ep = emb + (size_t)k * D;
        float s = 0.f;
        for (int d = tid; d < D; d += 256) {
            float v = ep[d];
            s += v * v;
            eb[(size_t)k * D + d] = __float2bfloat16(v);
        }
#pragma unroll
        for (int o = 32; o; o >>= 1) s += __shfl_down(s, o);
        __shared__ float ls[4];
        if ((tid & 63) == 0) ls[tid >> 6] = s;
        __syncthreads();
        if (tid == 0) esq[k] = ls[0] + ls[1] + ls[2] + ls[3];
    }
}

// ---------------- Kernel G4: 256x256 tile, 8-wave, BK=64 dbuf (unchanged — control) ----------------
__global__ __launch_bounds__(512, 2) void kg(const __hip_bfloat16* __restrict__ zb,
                                             const __hip_bfloat16* __restrict__ eb,
                                             const float* __restrict__ esq,
                                             unsigned int* __restrict__ minb) {
    __shared__ __hip_bfloat16 As[2][256 * 64];   // 32 KiB per slot
    __shared__ __hip_bfloat16 Bs[2][256 * 64];   // total 128 KiB

    int bid   = blockIdx.x;
    int swzb  = (bid & 7) * 64 + (bid >> 3);
    int mtile = swzb >> 3;            // 0..63
    int ntile = swzb & 7;             // 0..7

    int tid  = threadIdx.x;
    int wv   = tid >> 6;              // 0..7
    int lane = tid & 63;
    int wm   = wv >> 2, wnn = wv & 3; // 2x4 wave grid, wave tile 128(M) x 64(N)
    int lrow = lane & 15, lquad = lane >> 4;
    int rl8  = lane >> 3, c8 = lane & 7;     // staging: 8 rows x 8 uint4 per wave-call
    int csw  = c8 ^ (rl8 & 7);               // store-side swizzled global uint4 col
    int swz  = lrow & 7;                     // read-side swizzle key

    const uint4* Ag = (const uint4*)(zb + (size_t)mtile * 256 * D);  // row stride 64 uint4
    const uint4* Bg = (const uint4*)(eb + (size_t)ntile * 256 * D);

    floatx4 acc[8][4];
#pragma unroll
    for (int f = 0; f < 8; ++f)
#pragma unroll
        for (int g = 0; g < 4; ++g) acc[f][g] = (floatx4){0.f, 0.f, 0.f, 0.f};

#define STAGE(sl, t) do {                                                                  \
        _Pragma("unroll")                                                                  \
        for (int q = 0; q < 4; ++q) {                                                      \
            int rb = wv * 32 + q * 8;      /* wave-uniform row base */                     \
            GLD_LDS16(Ag + (size_t)(rb + rl8) * 64 + (t) * 8 + csw, &As[sl][rb * 64]);     \
            GLD_LDS16(Bg + (size_t)(rb + rl8) * 64 + (t) * 8 + csw, &Bs[sl][rb * 64]);     \
        }                                                                                  \
    } while (0)

#define STEP(sl) do {                                                                      \
        _Pragma("unroll")                                                                  \
        for (int kh = 0; kh < 2; ++kh) {                                                   \
            short8 bf[4], af[8];                                                           \
            const int cL = ((kh * 4 + lquad) ^ swz) << 3;                                  \
            _Pragma("unroll")                                                              \
            for (int g = 0; g < 4; ++g)                                                    \
                bf[g] = *(const short8*)&Bs[sl][(wnn * 64 + g * 16 + lrow) * 64 + cL];     \
            _Pragma("unroll")                                                              \
            for (int f = 0; f < 8; ++f)                                                    \
                af[f] = *(const short8*)&As[sl][(wm * 128 + f * 16 + lrow) * 64 + cL];     \
            _Pragma("unroll")                                                              \
            for (int f = 0; f < 8; ++f)                                                    \
                _Pragma("unroll")                                                          \
                for (int g = 0; g < 4; ++g)                                                \
                    acc[f][g] = __builtin_amdgcn_mfma_f32_16x16x32_bf16(af[f], bf[g],      \
                                                                        acc[f][g], 0, 0, 0);\
        }                                                                                  \
    } while (0)

    STAGE(0, 0);
    __syncthreads();

#pragma unroll
    for (int t = 0; t < 8; ++t) {
        if (t < 7) STAGE((t + 1) & 1, t + 1);
        STEP(t & 1);
        __syncthreads();
    }
#undef STAGE
#undef STEP

    float es[4];
#pragma unroll
    for (int g = 0; g < 4; ++g) es[g] = esq[ntile * 256 + wnn * 64 + g * 16 + lrow];

    unsigned int* scr = (unsigned int*)&As[0][0];
#pragma unroll
    for (int f = 0; f < 8; ++f) {
#pragma unroll
        for (int r = 0; r < 4; ++r) {
            unsigned int best = 0xFFFFFFFFu;
#pragma unroll
            for (int g = 0; g < 4; ++g) {
                float dist = es[g] - 2.0f * acc[f][g][r];
                unsigned int kidx = (unsigned int)(ntile * 256 + wnn * 64 + g * 16 + lrow);
                unsigned int p = (fkey(dist) & 0xFFFFF800u) | kidx;
                best = p < best ? p : best;
            }
#pragma unroll
            for (int o = 1; o < 16; o <<= 1) {
                unsigned int other = (unsigned int)__shfl_xor((int)best, o);
                best = other < best ? other : best;
            }
            if (lrow == 0)
                scr[wnn * 256 + wm * 128 + f * 16 + lquad * 4 + r] = best;
        }
    }
    __syncthreads();
    if (tid < 256) {
        unsigned int b0 = scr[tid];
        unsigned int b1 = scr[256 + tid];
        unsigned int b2 = scr[512 + tid];
        unsigned int b3 = scr[768 + tid];
        b0 = b1 < b0 ? b1 : b0;
        b2 = b3 < b2 ? b3 : b2;
        b0 = b2 < b0 ? b2 : b0;
        atomicMin(&minb[mtile * 256 + tid], b0);
    }
}

// ---------------- Kernel O5: gather + NCHW write + loss, CONTIGUOUS-WRITE panels ----------------
// R4 post-mortem: ko3 was write-BW-sunk (590 GB/s eff.) because every block emitted 256 B
// chunks at 4 KB stride, x2048 interleaved streams -> HBM row thrash. NCHW layout makes
// channels of one image contiguous, so: block = (image b, channel-group of 8) owns ONE
// CONTIGUOUS 32 KB output region. Gather emb (L2-resident, FETCH was 2.3 MB) into a
// transposed qt[8][1024] in LDS (2-way bank alias only = free), then a single linear
// coalesced 32 KB store. 1024 blocks x 256 thr, 36 KB LDS -> 4 blocks/CU (16 waves/CU).
// Loss partial: cg==0 block of each image sums its 1024 decoded keys -> parts[b] (16),
// cnt2 target 16; last one folds parts+pz and writes out[NUMEL].
__global__ __launch_bounds__(256) void ko3(const float* __restrict__ emb,
                                           const unsigned int* __restrict__ minb,
                                           const float* __restrict__ pz,
                                           float* __restrict__ out,
                                           float* __restrict__ parts,
                                           unsigned int* __restrict__ cnt2) {
    __shared__ int   idx[1024];      // 4 KB: codebook index per token of image b
    __shared__ float qt[8][1024];    // 32 KB: [channel][hw] = exact NCHW panel layout
    __shared__ float red[4];
    __shared__ int finflag;
    int blk = blockIdx.x;            // 0..1023
    int b   = blk >> 6;              // image 0..15
    int cg  = blk & 63;              // channel group 0..63 (8 channels each)
    int c0  = cg * 8;
    int tid = threadIdx.x;

    if (tid == 0) finflag = 0;

    // ---- load indices for all 1024 tokens of image b (+ loss decode in cg==0) ----
    float lv = 0.f;
#pragma unroll
    for (int i = 0; i < 4; ++i) {
        int t = tid + 256 * i;
        unsigned int key = minb[b * 1024 + t];
        idx[t] = (int)(key & 0x7FFu);
        if (cg == 0) lv += unfkey(key & 0xFFFFF800u);   // min(esq - 2 dot) per token
    }
    __syncthreads();                 // idx visible to all waves (covers finflag init too)

    if (cg == 0) {
#pragma unroll
        for (int o = 32; o; o >>= 1) lv += __shfl_down(lv, o);
        if ((tid & 63) == 0) red[tid >> 6] = lv;
        __syncthreads();
        if (tid == 0) {
            parts[b] = red[0] + red[1] + red[2] + red[3];
            __threadfence();
            finflag = (atomicAdd(cnt2, 1u) == 15u);
        }
    }

    // ---- gather: 1024 tokens x 8 channels; 2 lanes per token (2x16 B of the 32 B row cut) ----
    int half = tid & 1;              // which float4 of the 8-channel slice
    int tb   = tid >> 1;             // token sub-index 0..127
#pragma unroll
    for (int i = 0; i < 8; ++i) {
        int t = tb + 128 * i;
        float4 v = *(const float4*)(emb + (size_t)idx[t] * D + c0 + half * 4);
        // transpose into [channel][hw]; per instr: 32 tokens x 2 rows -> 2-way bank alias (free)
        qt[half * 4 + 0][t] = v.x; qt[half * 4 + 1][t] = v.y;
        qt[half * 4 + 2][t] = v.z; qt[half * 4 + 3][t] = v.w;
    }
    __syncthreads();

    // ---- single contiguous 32 KB store: qt[8][1024] IS the NCHW panel ----
    float4* ob = (float4*)(out + ((size_t)b * D + c0) * HW);
    const float4* qb = (const float4*)&qt[0][0];
#pragma unroll
    for (int i = 0; i < 8; ++i)
        ob[tid + 256 * i] = qb[tid + 256 * i];

    // ---- final loss reduce by the last-finishing cg==0 block ----
    __syncthreads();
    if (finflag) {
        float sv = (tid < 16) ? atomicAdd(&parts[tid], 0.0f) : 0.f;  // coherent read, 16 images
#pragma unroll
        for (int k8 = 0; k8 < 8; ++k8) sv += pz[tid * 8 + k8];       // fold 2048 z^2 partials
#pragma unroll
        for (int o = 32; o; o >>= 1) sv += __shfl_down(sv, o);
        if ((tid & 63) == 0) red[tid >> 6] = sv;
        __syncthreads();
        if (tid == 0)
            out[NUMEL] = 1.25f * (red[0] + red[1] + red[2] + red[3]) / 8388608.0f;
    }
}

extern "C" void kernel_launch(void* const* d_in, const int* in_sizes, int n_in,
                              void* d_out, int out_size, void* d_ws, size_t ws_size,
                              hipStream_t stream) {
    const float* z   = (const float*)d_in[0];   // [16,512,32,32]
    const float* emb = (const float*)d_in[1];   // [2048,512]
    char* ws = (char*)d_ws;
    __hip_bfloat16* zb   = (__hip_bfloat16*)(ws + WS_ZB);
    __hip_bfloat16* eb   = (__hip_bfloat16*)(ws + WS_EB);
    float*          esq  = (float*)(ws + WS_ESQ);
    unsigned int*   minb = (unsigned int*)(ws + WS_MINB);
    float*          pz   = (float*)(ws + WS_PZ);
    float*          parts= (float*)(ws + WS_PARTS);
    unsigned int*   cnt2 = (unsigned int*)(ws + WS_CNT2);
    float* out = (float*)d_out;

    kp <<<4096, 256, 0, stream>>>(z, emb, zb, eb, esq, pz, minb, cnt2);
    kg <<< 512, 512, 0, stream>>>(zb, eb, esq, minb);
    ko3<<<1024, 256, 0, stream>>>(emb, minb, pz, out, parts, cnt2);
}